// Round 7
// baseline (156.982 us; speedup 1.0000x reference)
//
#include <hip/hip_runtime.h>
#include <stdint.h>

typedef __attribute__((ext_vector_type(4))) int   i32x4v;
typedef __attribute__((ext_vector_type(16))) int  i32x16v;
typedef __attribute__((ext_vector_type(4))) float f32x4;

#define PIX 3136            // 56*56
#define WW 56
#define SLAB 215296         // 58*58*64 bytes, one (n,chunk64) plane
#define APLANE 5600         // LDS bytes per 16B-subchunk plane (350 units)
#define AWIN   22400        // 4 * APLANE
#define EPW    8704         // epilogue per-wave: 32 oc x 68 px x 4B
#define LDSB   34816        // max(AWIN, 4*EPW)

// workspace (bytes): two planar i8 tensors + transposed weights + flag
#define XBP_BYTES ((size_t)32*4*3364*64)          // 27,557,888
#define OFF_XBP2  (XBP_BYTES)
#define OFF_WBT   (2*XBP_BYTES)
#define WBT_BYTES ((size_t)9*16*256*16)           // 589,824
#define OFF_FLAG  (OFF_WBT + WBT_BYTES)
#define WS_NEED   (OFF_FLAG + 64)

__global__ void k_flag(const float* __restrict__ s1, const float* __restrict__ s2,
                       int* __restrict__ flag) {
    __shared__ int bad;
    int t = threadIdx.x;
    if (t == 0) bad = 0;
    __syncthreads();
    if (s1[t] != s2[t]) atomicAdd(&bad, 1);
    __syncthreads();
    if (t == 0) *flag = (bad == 0) ? 1 : 0;
}

// Zero only the 1-px halo ring of each 58x58x64 slab. 912 16B units per slab.
__global__ __launch_bounds__(256) void k_zero_halo(char* __restrict__ ws,
                                                   const int* __restrict__ flag) {
    int slab = blockIdx.x;                // 0..127 xbp1, 128..255 xbp2
    if (slab >= 128 && *flag != 0) return;
    char* base = ws + (size_t)slab * SLAB;
    int t = threadIdx.x;
    int4 z = {0, 0, 0, 0};
#pragma unroll
    for (int i = 0; i < 4; ++i) {
        int u = t + i * 256;
        if (u >= 912) break;
        int off;
        if (u < 232)      off = u;                               // top row
        else if (u < 464) off = 57 * 232 + (u - 232);            // bottom row
        else if (u < 688) { int r = (u - 464) >> 2; off = (r + 1) * 232 + ((u - 464) & 3); }
        else              { int r = (u - 688) >> 2; off = (r + 1) * 232 + 228 + ((u - 688) & 3); }
        *(int4*)(base + off * 16) = z;
    }
}

// wbTt[kk][sub16][oc256][16B]: c = sub*16 + lo
__global__ void k_repack_w(const float* __restrict__ w, char* __restrict__ wbTt) {
    int idx = blockIdx.x * 256 + threadIdx.x;     // 0..589823
    int kk = idx >> 16;
    int sub = (idx >> 12) & 15;
    int oc = (idx >> 4) & 255;
    int lo = idx & 15;
    int c = sub * 16 + lo;
    float v = w[(oc * 256 + c) * 9 + kk];
    wbTt[idx] = (v > 0.f) ? (char)1 : ((v < 0.f) ? (char)-1 : (char)0);
}

// NCHW fp32 -> planar halo-padded i8: xbp[n][plane4][py][px][64] = sign(x+shift)
__global__ __launch_bounds__(256) void k_repack_x(
    const float* __restrict__ x, const float* __restrict__ sh1,
    const float* __restrict__ sh2, char* __restrict__ xbp1,
    char* __restrict__ xbp2, const int* __restrict__ flag) {
    __shared__ float lds[64 * 68];
    bool eq = (*flag != 0);
    int t = threadIdx.x;
    int b = blockIdx.x;
    int n = b / 49;
    int p0 = (b % 49) * 64;

    int pixw = t >> 2;               // 0..63
    int sub  = t & 3;
    int pw = p0 + pixw;
    int yw = pw / WW, xw = pw % WW;

    int cl = t >> 4;
    int p4 = (t & 15) * 4;

    for (int cc = 0; cc < 256; cc += 64) {
        __syncthreads();
#pragma unroll
        for (int i = 0; i < 4; ++i) {
            float4 v = *(const float4*)(x + (size_t)(n * 256 + cc + cl + i * 16) * PIX + p0 + p4);
            *(float4*)(&lds[(cl + i * 16) * 68 + p4]) = v;
        }
        __syncthreads();
        size_t obase = (size_t)(n * 4 + (cc >> 6)) * SLAB
                     + ((size_t)(yw + 1) * 58 + (xw + 1)) * 64 + sub * 16;
        union { char c[16]; int4 v; } u1, u2;
#pragma unroll
        for (int k = 0; k < 16; ++k) {
            int c = sub * 16 + k;
            float v = lds[c * 68 + pixw];
            float a1 = v + sh1[cc + c];
            float a2 = v + sh2[cc + c];
            u1.c[k] = (a1 > 0.f) ? (char)1 : ((a1 < 0.f) ? (char)-1 : (char)0);
            u2.c[k] = (a2 > 0.f) ? (char)1 : ((a2 < 0.f) ? (char)-1 : (char)0);
        }
        *(int4*)(xbp1 + obase) = u1.v;
        if (!eq) *(int4*)(xbp2 + obase) = u2.v;
    }
}

// Implicit-GEMM binary conv, i8 MFMA. Tile 128px x 64oc, 4 waves (2px x 2oc),
// wave = 64px x 32oc -> acc 32 AGPR. B: L2->reg, 2 taps ahead (bf[3] rotation).
// A window in LDS, reused across 9 taps, 2 barriers per cc.
// MODE 0: EQ: out=(acc+b)*(1+w1). MODE 1: out=acc+(1+w1)b. MODE 2: out+=w1*acc.
template <int MODE>
__global__ __launch_bounds__(256, 4) void k_bgemm(
    const char* __restrict__ xsrc, const char* __restrict__ wbTt,
    const float* __restrict__ bias, const float* __restrict__ w1,
    const int* __restrict__ flag, float* __restrict__ out) {
    bool eq = (*flag != 0);
    if (MODE == 0 ? !eq : eq) return;    // block-uniform

    __shared__ char lds[LDSB];

    int t = threadIdx.x;
    int l = t & 63, wid = t >> 6;
    int wr = wid >> 1, wc = wid & 1;
    int r32 = l & 31, half = l >> 5;

    // XCD-chunked swizzle: 3200 blocks, 400/XCD; 4 oc-tiles of one window adjacent
    int logical = (blockIdx.x & 7) * 400 + (blockIdx.x >> 3);
    int ntile = logical & 3;
    int m = logical >> 2;                // 0..799
    int n = m / 25, tp = m % 25;
    int p0 = tp * 128;
    int y0 = p0 / WW;
    int pyw0 = (y0 < 52) ? y0 : 52;      // window rows pyw0..pyw0+5
    int ocb = ntile * 64 + wc * 32;      // this wave's absolute oc base
    int n4 = n * 4;

    int wpm[2];
#pragma unroll
    for (int mi = 0; mi < 2; ++mi) {
        int g = p0 + wr * 64 + mi * 32 + r32;
        if (g > 3135) g = 3135;          // only in fully-discarded waves
        int y = g / WW, xx = g - y * WW;
        wpm[mi] = (y + 1 - pyw0) * 58 + xx + 1;
    }

    int4 rA[6];
    i32x4v bf[3][2];                     // [rot][kq]

    auto loadRA = [&](int cc_) {
        const char* sb = xsrc + (size_t)(n4 + cc_) * SLAB + (size_t)pyw0 * 3712;
#pragma unroll
        for (int j = 0; j < 6; ++j) {
            int u = t + j * 256;
            if (u < 1392) rA[j] = *(const int4*)(sb + u * 16);
        }
    };
    auto writeA = [&]() {
#pragma unroll
        for (int j = 0; j < 6; ++j) {
            int u = t + j * 256;
            if (u < 1392) *(int4*)(lds + (u & 3) * APLANE + (u >> 2) * 16) = rA[j];
        }
    };
    auto loadB = [&](int rot, int cc_, int kk_) {
#pragma unroll
        for (int kq = 0; kq < 2; ++kq)
            bf[rot][kq] = *(const i32x4v*)(wbTt +
                (((size_t)((kk_ * 16 + cc_ * 4 + kq * 2 + half) * 256
                           + ocb + r32)) << 4));
    };

    i32x16v acc[2];
#pragma unroll
    for (int mi = 0; mi < 2; ++mi)
#pragma unroll
        for (int i = 0; i < 16; ++i) acc[mi][i] = 0;

    // prologue: A window for cc=0; B for taps 0 and 1
    loadRA(0);
    loadB(0, 0, 0);
    loadB(1, 0, 1);

#pragma unroll
    for (int cc = 0; cc < 4; ++cc) {
        __syncthreads();                 // all waves done reading old window
        writeA();
        __syncthreads();                 // window ready
#pragma unroll
        for (int kk = 0; kk < 9; ++kk) {
            const int s = cc * 9 + kk;
            if (s + 2 <= 35) loadB((s + 2) % 3, (s + 2) / 9, (s + 2) % 9);
            if (kk == 7 && cc < 3) loadRA(cc + 1);
            const int ts = (kk / 3 - 1) * 58 + (kk % 3) - 1;
            const int cur = s % 3;
#pragma unroll
            for (int kq = 0; kq < 2; ++kq) {
                int ci = kq * 2 + half;
                i32x4v af0 = *(const i32x4v*)(lds + ci * APLANE + (wpm[0] + ts) * 16);
                i32x4v af1 = *(const i32x4v*)(lds + ci * APLANE + (wpm[1] + ts) * 16);
                acc[0] = __builtin_amdgcn_mfma_i32_32x32x32_i8(af0, bf[cur][kq], acc[0], 0, 0, 0);
                acc[1] = __builtin_amdgcn_mfma_i32_32x32x32_i8(af1, bf[cur][kq], acc[1], 0, 0, 0);
            }
        }
    }

    // ---- epilogue: per-wave LDS transpose -> 256B-contiguous stores ----
    __syncthreads();                     // A window dead; reuse as 4 x 8704B
    float w1v = w1[0];
    float se = 1.f + w1v;
    float* sb = (float*)(lds + wid * EPW);   // [32 oc][68 px]
    float bv = bias[ocb + r32];
    int pxb = p0 + wr * 64;
    bool pvalid = pxb < PIX;

#pragma unroll
    for (int mi = 0; mi < 2; ++mi) {
#pragma unroll
        for (int q = 0; q < 4; ++q) {
            f32x4 v;
#pragma unroll
            for (int j = 0; j < 4; ++j) {
                float a = (float)(acc[mi][q * 4 + j]);
                if (MODE == 0)      v[j] = (a + bv) * se;
                else if (MODE == 1) v[j] = a + se * bv;
                else                v[j] = w1v * a;
            }
            *(f32x4*)(sb + r32 * 68 + mi * 32 + q * 8 + half * 4) = v;
        }
    }
    __syncthreads();
    if (pvalid) {
#pragma unroll
        for (int step = 0; step < 8; ++step) {
            int row = step * 4 + (l >> 4);       // oc-rel 0..31
            int pxq = (l & 15) * 4;              // px-rel 0..60
            f32x4 v = *(const f32x4*)(sb + row * 68 + pxq);
            float* op = out + ((size_t)(n * 256 + ocb + row)) * PIX + pxb + pxq;
            if (MODE == 2) {
                f32x4 o = *(const f32x4*)op;
                v[0] += o[0]; v[1] += o[1]; v[2] += o[2]; v[3] += o[3];
            }
            *(f32x4*)op = v;
        }
    }
}

extern "C" void kernel_launch(void* const* d_in, const int* in_sizes, int n_in,
                              void* d_out, int out_size, void* d_ws, size_t ws_size,
                              hipStream_t stream) {
    const float* x    = (const float*)d_in[0];
    const float* sh1  = (const float*)d_in[1];
    const float* sh2  = (const float*)d_in[2];
    const float* wgt  = (const float*)d_in[3];
    const float* bias = (const float*)d_in[4];
    const float* w1   = (const float*)d_in[5];
    float* out = (float*)d_out;
    char* ws = (char*)d_ws;
    if (ws_size < WS_NEED) return;

    char* xbp1 = ws;
    char* xbp2 = ws + OFF_XBP2;
    char* wbTt = ws + OFF_WBT;
    int* flag  = (int*)(ws + OFF_FLAG);

    k_flag<<<1, 256, 0, stream>>>(sh1, sh2, flag);
    k_zero_halo<<<256, 256, 0, stream>>>(ws, flag);
    k_repack_w<<<2304, 256, 0, stream>>>(wgt, wbTt);
    k_repack_x<<<32 * 49, 256, 0, stream>>>(x, sh1, sh2, xbp1, xbp2, flag);
    k_bgemm<0><<<3200, 256, 0, stream>>>(xbp1, wbTt, bias, w1, flag, out);
    k_bgemm<1><<<3200, 256, 0, stream>>>(xbp1, wbTt, bias, w1, flag, out);
    k_bgemm<2><<<3200, 256, 0, stream>>>(xbp2, wbTt, bias, w1, flag, out);
}

// Round 8
// 145.309 us; speedup vs baseline: 1.0803x; 1.0803x over previous
//
#include <hip/hip_runtime.h>
#include <stdint.h>

typedef __attribute__((ext_vector_type(4))) int   i32x4v;
typedef __attribute__((ext_vector_type(16))) int  i32x16v;
typedef __attribute__((ext_vector_type(4))) float f32x4;

#define PIX 3136            // 56*56
#define WW 56
#define SLAB 215296         // 58*58*64 bytes, one (n,chunk64) plane
#define APL 3712            // LDS bytes per 16B-sub plane: 4 rows * 58 * 16
#define WIN16 928           // 16B units per window (4*58*4)
#define LDSB 17152          // epilogue [64][67] f32 dominates (A window 14848)

// workspace (bytes): two planar i8 tensors + transposed weights + flag
#define XBP_BYTES ((size_t)32*4*3364*64)          // 27,557,888
#define OFF_XBP2  (XBP_BYTES)
#define OFF_WBT   (2*XBP_BYTES)
#define WBT_BYTES ((size_t)9*16*256*16)           // 589,824
#define OFF_FLAG  (OFF_WBT + WBT_BYTES)
#define WS_NEED   (OFF_FLAG + 64)

// Fused prologue: block 0 = flag; blocks 1..256 = halo-zero (both tensors);
// blocks 257..2560 = weight repack.
__global__ __launch_bounds__(256) void k_prep(
    const float* __restrict__ s1, const float* __restrict__ s2,
    const float* __restrict__ w, char* __restrict__ ws,
    char* __restrict__ wbTt, int* __restrict__ flag) {
    int b = blockIdx.x;
    int t = threadIdx.x;
    if (b == 0) {
        __shared__ int bad;
        if (t == 0) bad = 0;
        __syncthreads();
        if (s1[t] != s2[t]) atomicAdd(&bad, 1);
        __syncthreads();
        if (t == 0) *flag = (bad == 0) ? 1 : 0;
        return;
    }
    if (b <= 256) {
        char* base = ws + (size_t)(b - 1) * SLAB;
        int4 z = {0, 0, 0, 0};
#pragma unroll
        for (int i = 0; i < 4; ++i) {
            int u = t + i * 256;
            if (u >= 912) break;
            int off;
            if (u < 232)      off = u;                               // top row
            else if (u < 464) off = 57 * 232 + (u - 232);            // bottom row
            else if (u < 688) { int r = (u - 464) >> 2; off = (r + 1) * 232 + ((u - 464) & 3); }
            else              { int r = (u - 688) >> 2; off = (r + 1) * 232 + 228 + ((u - 688) & 3); }
            *(int4*)(base + off * 16) = z;
        }
        return;
    }
    // weight repack: wbTt[kk][sub16][oc256][16B], c = sub*16 + lo
    int idx = (b - 257) * 256 + t;               // 0..589823
    int kk = idx >> 16;
    int sub = (idx >> 12) & 15;
    int oc = (idx >> 4) & 255;
    int lo = idx & 15;
    float v = w[(oc * 256 + sub * 16 + lo) * 9 + kk];
    wbTt[idx] = (v > 0.f) ? (char)1 : ((v < 0.f) ? (char)-1 : (char)0);
}

// NCHW fp32 -> planar halo-padded i8: xbp[n][plane4][py][px][64] = sign(x+shift)
__global__ __launch_bounds__(256) void k_repack_x(
    const float* __restrict__ x, const float* __restrict__ sh1,
    const float* __restrict__ sh2, char* __restrict__ xbp1,
    char* __restrict__ xbp2, const int* __restrict__ flag) {
    __shared__ float lds[64 * 68];
    bool eq = (*flag != 0);
    int t = threadIdx.x;
    int b = blockIdx.x;
    int n = b / 49;
    int p0 = (b % 49) * 64;

    int pixw = t >> 2;               // 0..63
    int sub  = t & 3;
    int pw = p0 + pixw;
    int yw = pw / WW, xw = pw % WW;

    int cl = t >> 4;
    int p4 = (t & 15) * 4;

    for (int cc = 0; cc < 256; cc += 64) {
        __syncthreads();
#pragma unroll
        for (int i = 0; i < 4; ++i) {
            float4 v = *(const float4*)(x + (size_t)(n * 256 + cc + cl + i * 16) * PIX + p0 + p4);
            *(float4*)(&lds[(cl + i * 16) * 68 + p4]) = v;
        }
        __syncthreads();
        size_t obase = (size_t)(n * 4 + (cc >> 6)) * SLAB
                     + ((size_t)(yw + 1) * 58 + (xw + 1)) * 64 + sub * 16;
        union { char c[16]; int4 v; } u1, u2;
#pragma unroll
        for (int k = 0; k < 16; ++k) {
            int c = sub * 16 + k;
            float v = lds[c * 68 + pixw];
            float a1 = v + sh1[cc + c];
            float a2 = v + sh2[cc + c];
            u1.c[k] = (a1 > 0.f) ? (char)1 : ((a1 < 0.f) ? (char)-1 : (char)0);
            u2.c[k] = (a2 > 0.f) ? (char)1 : ((a2 < 0.f) ? (char)-1 : (char)0);
        }
        *(int4*)(xbp1 + obase) = u1.v;
        if (!eq) *(int4*)(xbp2 + obase) = u2.v;
    }
}

// Implicit-GEMM binary conv, i8 MFMA. Tile 64px x 256oc (ALL oc -> A fetched once).
// 4 waves (2 px-groups x 2 oc-halves), wave = 32px x 128oc, acc = 4 x 16 = 64 AGPR.
// A window (4 rows x 58 x 64 = 14.8KB) in LDS, reused across 9 taps & 4 kq... taps.
// B: L2->reg, 3-slot kq-granular rotation (1 stage lookahead), no B LDS.
// MODE 0: EQ: out=(acc+b)*(1+w1). MODE 1: out=acc+(1+w1)b. MODE 2: out+=w1*acc.
template <int MODE>
__global__ __launch_bounds__(256, 3) void k_bgemm(
    const char* __restrict__ xsrc, const char* __restrict__ wbTt,
    const float* __restrict__ bias, const float* __restrict__ w1,
    const int* __restrict__ flag, float* __restrict__ out) {
    bool eq = (*flag != 0);
    if (MODE == 0 ? !eq : eq) return;    // block-uniform

    __shared__ char lds[LDSB];

    int t = threadIdx.x;
    int l = t & 63, wid = t >> 6;
    int wr = wid >> 1, wc = wid & 1;
    int r32 = l & 31, half = l >> 5;

    // XCD-chunked swizzle: 1568 = 8*196; consecutive logicals share window rows
    int logical = (blockIdx.x & 7) * 196 + (blockIdx.x >> 3);
    int n = logical / 49, tp = logical % 49;
    int p0 = tp * 64;
    int y0 = p0 / WW;                    // window = padded rows y0..y0+3
    int ocw = wc * 128;

    int g = p0 + wr * 32 + r32;          // always < 3136 (49*64 = 3136 exact)
    int yg = g / WW, xg = g - yg * WW;
    int wpm = (yg + 1 - y0) * 58 + xg + 1;

    int4 rA[4];
    i32x4v bf[3][4];                     // [rot][ni]

    auto loadRA = [&](int cc_) {
        const char* sb = xsrc + (size_t)(n * 4 + cc_) * SLAB + (size_t)y0 * 3712;
#pragma unroll
        for (int j = 0; j < 4; ++j) {
            int u = t + j * 256;
            if (u < WIN16) rA[j] = *(const int4*)(sb + u * 16);
        }
    };
    auto writeA = [&]() {
#pragma unroll
        for (int j = 0; j < 4; ++j) {
            int u = t + j * 256;
            if (u < WIN16) *(int4*)(lds + (u & 3) * APL + (u >> 2) * 16) = rA[j];
        }
    };
    auto loadB = [&](int rot, int sk) {  // sk = cc*18 + kk*2 + kq, all compile-time
        int cc_ = sk / 18, kk_ = (sk / 2) % 9, kq_ = sk & 1;
#pragma unroll
        for (int ni = 0; ni < 4; ++ni)
            bf[rot][ni] = *(const i32x4v*)(wbTt +
                (((size_t)((kk_ * 16 + cc_ * 4 + kq_ * 2 + half) * 256
                           + ocw + ni * 32 + r32)) << 4));
    };

    i32x16v acc[4];
#pragma unroll
    for (int ni = 0; ni < 4; ++ni)
#pragma unroll
        for (int i = 0; i < 16; ++i) acc[ni][i] = 0;

    loadRA(0);
    loadB(0, 0);
    loadB(1, 1);

#pragma unroll
    for (int cc = 0; cc < 4; ++cc) {
        __syncthreads();                 // all waves done reading old window
        writeA();
        __syncthreads();                 // window ready
#pragma unroll
        for (int kk = 0; kk < 9; ++kk) {
            const int ts = (kk / 3 - 1) * 58 + (kk % 3) - 1;
#pragma unroll
            for (int kq = 0; kq < 2; ++kq) {
                const int sk = cc * 18 + kk * 2 + kq;
                if (sk + 2 < 72) loadB((sk + 2) % 3, sk + 2);
                // A for next cc: issued late (after this phase's B) so in-order
                // vmcnt never parks the HBM A-load in front of a B wait.
                if (kk == 7 && kq == 1 && cc < 3) loadRA(cc + 1);
                const int ci = kq * 2 + half;
                i32x4v af = *(const i32x4v*)(lds + ci * APL + (wpm + ts) * 16);
                const int cur = sk % 3;
#pragma unroll
                for (int ni = 0; ni < 4; ++ni)
                    acc[ni] = __builtin_amdgcn_mfma_i32_32x32x32_i8(
                        af, bf[cur][ni], acc[ni], 0, 0, 0);
            }
        }
    }

    // ---- epilogue: per-ni LDS transpose [64 oc][67 px-pad] -> 256B-line stores ----
    __syncthreads();
    float w1v = w1[0];
    float se = 1.f + w1v;
    float* sb = (float*)lds;
    size_t outb = (size_t)n * 256 * PIX + p0;

#pragma unroll
    for (int ni = 0; ni < 4; ++ni) {
        float bv = bias[ocw + ni * 32 + r32];
#pragma unroll
        for (int q = 0; q < 4; ++q) {
            f32x4 v;
#pragma unroll
            for (int j = 0; j < 4; ++j) {
                float a = (float)(acc[ni][q * 4 + j]);
                if (MODE == 0)      v[j] = (a + bv) * se;
                else if (MODE == 1) v[j] = a + se * bv;
                else                v[j] = w1v * a;
            }
            *(f32x4*)(sb + (wc * 32 + r32) * 67 + wr * 32 + q * 8 + half * 4) = v;
        }
        __syncthreads();
#pragma unroll
        for (int p = 0; p < 4; ++p) {
            int oi = p * 16 + (t >> 4);          // 0..63
            int px4 = (t & 15) * 4;              // 0..60
            f32x4 v = *(const f32x4*)(sb + oi * 67 + px4);
            int ocA = (oi >> 5) * 128 + ni * 32 + (oi & 31);
            float* op = out + outb + (size_t)ocA * PIX + px4;
            if (MODE == 2) {
                f32x4 o = *(const f32x4*)op;
                v[0] += o[0]; v[1] += o[1]; v[2] += o[2]; v[3] += o[3];
            }
            *(f32x4*)op = v;
        }
        if (ni < 3) __syncthreads();
    }
}

extern "C" void kernel_launch(void* const* d_in, const int* in_sizes, int n_in,
                              void* d_out, int out_size, void* d_ws, size_t ws_size,
                              hipStream_t stream) {
    const float* x    = (const float*)d_in[0];
    const float* sh1  = (const float*)d_in[1];
    const float* sh2  = (const float*)d_in[2];
    const float* wgt  = (const float*)d_in[3];
    const float* bias = (const float*)d_in[4];
    const float* w1   = (const float*)d_in[5];
    float* out = (float*)d_out;
    char* ws = (char*)d_ws;
    if (ws_size < WS_NEED) return;

    char* xbp1 = ws;
    char* xbp2 = ws + OFF_XBP2;
    char* wbTt = ws + OFF_WBT;
    int* flag  = (int*)(ws + OFF_FLAG);

    k_prep<<<2561, 256, 0, stream>>>(sh1, sh2, wgt, ws, wbTt, flag);
    k_repack_x<<<32 * 49, 256, 0, stream>>>(x, sh1, sh2, xbp1, xbp2, flag);
    k_bgemm<0><<<1568, 256, 0, stream>>>(xbp1, wbTt, bias, w1, flag, out);
    k_bgemm<1><<<1568, 256, 0, stream>>>(xbp1, wbTt, bias, w1, flag, out);
    k_bgemm<2><<<1568, 256, 0, stream>>>(xbp2, wbTt, bias, w1, flag, out);
}

// Round 10
// 120.058 us; speedup vs baseline: 1.3076x; 1.2103x over previous
//
#include <hip/hip_runtime.h>
#include <stdint.h>

typedef __attribute__((ext_vector_type(4))) int   i32x4v;
typedef __attribute__((ext_vector_type(16))) int  i32x16v;
typedef __attribute__((ext_vector_type(4))) float f32x4;

#define PIX 3136            // 56*56
#define WW 56
#define SLAB 215296         // 58*58*64 bytes, one (n,chunk64) plane
#define APL 3712            // LDS bytes per 16B-sub plane: 4 rows * 58 * 16
#define WIN16 928           // 16B units per window (4*58*4)
#define EPQ (32*69*4)       // epilogue per-wave quadrant: [32 oc][69 px] f32 = 8832B
#define LDSB (4*EPQ)        // 35328 (A window 14848 fits inside)

// workspace (bytes): two planar i8 tensors + transposed weights + flag
#define XBP_BYTES ((size_t)32*4*3364*64)          // 27,557,888
#define OFF_XBP2  (XBP_BYTES)
#define OFF_WBT   (2*XBP_BYTES)
#define WBT_BYTES ((size_t)9*16*256*16)           // 589,824
#define OFF_FLAG  (OFF_WBT + WBT_BYTES)
#define WS_NEED   (OFF_FLAG + 64)

// Fused prologue: block 0 = flag; blocks 1..256 = halo-zero; 257.. = w repack.
__global__ __launch_bounds__(256) void k_prep(
    const float* __restrict__ s1, const float* __restrict__ s2,
    const float* __restrict__ w, char* __restrict__ ws,
    char* __restrict__ wbTt, int* __restrict__ flag) {
    int b = blockIdx.x;
    int t = threadIdx.x;
    if (b == 0) {
        __shared__ int bad;
        if (t == 0) bad = 0;
        __syncthreads();
        if (s1[t] != s2[t]) atomicAdd(&bad, 1);
        __syncthreads();
        if (t == 0) *flag = (bad == 0) ? 1 : 0;
        return;
    }
    if (b <= 256) {
        char* base = ws + (size_t)(b - 1) * SLAB;
        int4 z = {0, 0, 0, 0};
#pragma unroll
        for (int i = 0; i < 4; ++i) {
            int u = t + i * 256;
            if (u >= 912) break;
            int off;
            if (u < 232)      off = u;
            else if (u < 464) off = 57 * 232 + (u - 232);
            else if (u < 688) { int r = (u - 464) >> 2; off = (r + 1) * 232 + ((u - 464) & 3); }
            else              { int r = (u - 688) >> 2; off = (r + 1) * 232 + 228 + ((u - 688) & 3); }
            *(int4*)(base + off * 16) = z;
        }
        return;
    }
    int idx = (b - 257) * 256 + t;               // 0..589823
    int kk = idx >> 16;
    int sub = (idx >> 12) & 15;
    int oc = (idx >> 4) & 255;
    int lo = idx & 15;
    float v = w[(oc * 256 + sub * 16 + lo) * 9 + kk];
    wbTt[idx] = (v > 0.f) ? (char)1 : ((v < 0.f) ? (char)-1 : (char)0);
}

// NCHW fp32 -> planar halo-padded i8: xbp[n][plane4][py][px][64] = sign(x+shift)
__global__ __launch_bounds__(256) void k_repack_x(
    const float* __restrict__ x, const float* __restrict__ sh1,
    const float* __restrict__ sh2, char* __restrict__ xbp1,
    char* __restrict__ xbp2, const int* __restrict__ flag) {
    __shared__ float lds[64 * 68];
    bool eq = (*flag != 0);
    int t = threadIdx.x;
    int b = blockIdx.x;
    int n = b / 49;
    int p0 = (b % 49) * 64;

    int pixw = t >> 2;
    int sub  = t & 3;
    int pw = p0 + pixw;
    int yw = pw / WW, xw = pw % WW;

    int cl = t >> 4;
    int p4 = (t & 15) * 4;

    for (int cc = 0; cc < 256; cc += 64) {
        __syncthreads();
#pragma unroll
        for (int i = 0; i < 4; ++i) {
            float4 v = *(const float4*)(x + (size_t)(n * 256 + cc + cl + i * 16) * PIX + p0 + p4);
            *(float4*)(&lds[(cl + i * 16) * 68 + p4]) = v;
        }
        __syncthreads();
        size_t obase = (size_t)(n * 4 + (cc >> 6)) * SLAB
                     + ((size_t)(yw + 1) * 58 + (xw + 1)) * 64 + sub * 16;
        union { char c[16]; int4 v; } u1, u2;
#pragma unroll
        for (int k = 0; k < 16; ++k) {
            int c = sub * 16 + k;
            float v = lds[c * 68 + pixw];
            float a1 = v + sh1[cc + c];
            float a2 = v + sh2[cc + c];
            u1.c[k] = (a1 > 0.f) ? (char)1 : ((a1 < 0.f) ? (char)-1 : (char)0);
            u2.c[k] = (a2 > 0.f) ? (char)1 : ((a2 < 0.f) ? (char)-1 : (char)0);
        }
        *(int4*)(xbp1 + obase) = u1.v;
        if (!eq) *(int4*)(xbp2 + obase) = u2.v;
    }
}

// Implicit-GEMM binary conv, i8 MFMA. Tile 64px x 256oc; 4 waves, wave = 64px x 64oc
// (acc 2x2x16 = 64 AGPR). Per phase: 2 bf L2->reg loads, 2 af ds_reads, 4 MFMA.
// bf ring: SIZE 6, prefetch DISTANCE 5 (5 % 6 != 0 -> no consume/prefetch slot
// collision; round 9's 5/5 ring aliased and fed MFMA the wrong B). 48 VGPR.
// Nontemporal out stores keep the 103MB stream out of L2.
// MODE 0: EQ: out=(acc+b)*(1+w1). MODE 1: out=acc+(1+w1)b. MODE 2: out+=w1*acc.
template <int MODE>
__global__ __launch_bounds__(256, 3) void k_bgemm(
    const char* __restrict__ xsrc, const char* __restrict__ wbTt,
    const float* __restrict__ bias, const float* __restrict__ w1,
    const int* __restrict__ flag, float* __restrict__ out) {
    bool eq = (*flag != 0);
    if (MODE == 0 ? !eq : eq) return;    // block-uniform

    __shared__ char lds[LDSB];

    int t = threadIdx.x;
    int l = t & 63, wid = t >> 6;
    int r32 = l & 31, half = l >> 5;

    // XCD-chunked swizzle: 1568 = 8*196; consecutive logicals share window rows
    int logical = (blockIdx.x & 7) * 196 + (blockIdx.x >> 3);
    int n = logical / 49, tp = logical % 49;
    int p0 = tp * 64;
    int y0 = p0 / WW;                    // window = padded rows y0..y0+3
    int ocw = wid * 64;                  // this wave's 64-oc slice

    int wpm[2];
#pragma unroll
    for (int mi = 0; mi < 2; ++mi) {
        int g = p0 + mi * 32 + r32;      // < 3136 always
        int yg = g / WW, xg = g - yg * WW;
        wpm[mi] = (yg + 1 - y0) * 58 + xg + 1;
    }

    int4 rA[4];
    i32x4v bf[6][2];                     // [ring][nj]

    auto loadRA = [&](int cc_) {
        const char* sb = xsrc + (size_t)(n * 4 + cc_) * SLAB + (size_t)y0 * 3712;
#pragma unroll
        for (int j = 0; j < 4; ++j) {
            int u = t + j * 256;
            if (u < WIN16) rA[j] = *(const int4*)(sb + u * 16);
        }
    };
    auto writeA = [&]() {
#pragma unroll
        for (int j = 0; j < 4; ++j) {
            int u = t + j * 256;
            if (u < WIN16) *(int4*)(lds + (u & 3) * APL + (u >> 2) * 16) = rA[j];
        }
    };
    auto loadB = [&](int rot, int sk) {  // sk = cc*18 + kk*2 + kq (compile-time)
        int cc_ = sk / 18, kk_ = (sk / 2) % 9, kq_ = sk & 1;
#pragma unroll
        for (int nj = 0; nj < 2; ++nj)
            bf[rot][nj] = *(const i32x4v*)(wbTt +
                (((size_t)((kk_ * 16 + cc_ * 4 + kq_ * 2 + half) * 256
                           + ocw + nj * 32 + r32)) << 4));
    };

    i32x16v acc[2][2];                   // [mi][nj]
#pragma unroll
    for (int mi = 0; mi < 2; ++mi)
#pragma unroll
        for (int nj = 0; nj < 2; ++nj)
#pragma unroll
            for (int i = 0; i < 16; ++i) acc[mi][nj][i] = 0;

    // invariant: B for phase sk lives in ring slot sk % 6
    loadRA(0);
    loadB(0, 0); loadB(1, 1); loadB(2, 2); loadB(3, 3); loadB(4, 4);

#pragma unroll
    for (int cc = 0; cc < 4; ++cc) {
        __syncthreads();                 // all waves done reading old window
        writeA();
        __syncthreads();                 // window ready
#pragma unroll
        for (int kk = 0; kk < 9; ++kk) {
            const int ts = (kk / 3 - 1) * 58 + (kk % 3) - 1;
#pragma unroll
            for (int kq = 0; kq < 2; ++kq) {
                const int sk = cc * 18 + kk * 2 + kq;
                if (sk + 5 < 72) loadB((sk + 5) % 6, sk + 5);
                // A for next cc issued late so in-order vmcnt keeps B waits clean
                if (kk == 7 && kq == 1 && cc < 3) loadRA(cc + 1);
                const int ci = kq * 2 + half;
                i32x4v af0 = *(const i32x4v*)(lds + ci * APL + (wpm[0] + ts) * 16);
                i32x4v af1 = *(const i32x4v*)(lds + ci * APL + (wpm[1] + ts) * 16);
                const int cur = sk % 6;
                acc[0][0] = __builtin_amdgcn_mfma_i32_32x32x32_i8(af0, bf[cur][0], acc[0][0], 0, 0, 0);
                acc[0][1] = __builtin_amdgcn_mfma_i32_32x32x32_i8(af0, bf[cur][1], acc[0][1], 0, 0, 0);
                acc[1][0] = __builtin_amdgcn_mfma_i32_32x32x32_i8(af1, bf[cur][0], acc[1][0], 0, 0, 0);
                acc[1][1] = __builtin_amdgcn_mfma_i32_32x32x32_i8(af1, bf[cur][1], acc[1][1], 0, 0, 0);
            }
        }
    }

    // ---- epilogue: wave-private LDS transpose quadrant -> 256B nt stores ----
    __syncthreads();   // REQUIRED: quadrants overlay the A-window other waves read
    float w1v = w1[0];
    float se = 1.f + w1v;
    float* sb = (float*)(lds + wid * EPQ);   // [32 oc][69 px]
    size_t outb = (size_t)n * 256 * PIX + p0;

#pragma unroll
    for (int nj = 0; nj < 2; ++nj) {
        float bv = bias[ocw + nj * 32 + r32];
#pragma unroll
        for (int mi = 0; mi < 2; ++mi)
#pragma unroll
            for (int q = 0; q < 4; ++q) {
                f32x4 v;
#pragma unroll
                for (int j = 0; j < 4; ++j) {
                    float a = (float)(acc[mi][nj][q * 4 + j]);
                    if (MODE == 0)      v[j] = (a + bv) * se;
                    else if (MODE == 1) v[j] = a + se * bv;
                    else                v[j] = w1v * a;
                }
                *(f32x4*)(sb + r32 * 69 + mi * 32 + q * 8 + half * 4) = v;
            }
        asm volatile("s_waitcnt lgkmcnt(0)" ::: "memory");
#pragma unroll
        for (int p = 0; p < 8; ++p) {
            int row = p * 4 + (l >> 4);          // oc-rel 0..31
            int px4 = (l & 15) * 4;              // 0..60
            f32x4 v = *(const f32x4*)(sb + row * 69 + px4);
            float* op = out + outb + (size_t)(ocw + nj * 32 + row) * PIX + px4;
            if (MODE == 2) {
                f32x4 o = *(const f32x4*)op;
                v[0] += o[0]; v[1] += o[1]; v[2] += o[2]; v[3] += o[3];
            }
            __builtin_nontemporal_store(v, (f32x4*)op);
        }
        if (nj == 0) asm volatile("s_waitcnt lgkmcnt(0)" ::: "memory");
    }
}

extern "C" void kernel_launch(void* const* d_in, const int* in_sizes, int n_in,
                              void* d_out, int out_size, void* d_ws, size_t ws_size,
                              hipStream_t stream) {
    const float* x    = (const float*)d_in[0];
    const float* sh1  = (const float*)d_in[1];
    const float* sh2  = (const float*)d_in[2];
    const float* wgt  = (const float*)d_in[3];
    const float* bias = (const float*)d_in[4];
    const float* w1   = (const float*)d_in[5];
    float* out = (float*)d_out;
    char* ws = (char*)d_ws;
    if (ws_size < WS_NEED) return;

    char* xbp1 = ws;
    char* xbp2 = ws + OFF_XBP2;
    char* wbTt = ws + OFF_WBT;
    int* flag  = (int*)(ws + OFF_FLAG);

    k_prep<<<2561, 256, 0, stream>>>(sh1, sh2, wgt, ws, wbTt, flag);
    k_repack_x<<<32 * 49, 256, 0, stream>>>(x, sh1, sh2, xbp1, xbp2, flag);
    k_bgemm<0><<<1568, 256, 0, stream>>>(xbp1, wbTt, bias, w1, flag, out);
    k_bgemm<1><<<1568, 256, 0, stream>>>(xbp1, wbTt, bias, w1, flag, out);
    k_bgemm<2><<<1568, 256, 0, stream>>>(xbp2, wbTt, bias, w1, flag, out);
}

// Round 11
// 118.458 us; speedup vs baseline: 1.3252x; 1.0135x over previous
//
#include <hip/hip_runtime.h>
#include <stdint.h>

typedef __attribute__((ext_vector_type(4))) int   i32x4v;
typedef __attribute__((ext_vector_type(16))) int  i32x16v;
typedef __attribute__((ext_vector_type(4))) float f32x4;

#define PIX 3136            // 56*56
#define WW 56
#define SLAB 215296         // 58*58*64 bytes, one (n,chunk64) plane (global)
#define GROW 3712           // global bytes per padded row window-slice (58*64)
#define APL 3776            // LDS bytes per 16B-sub plane: 232*16 + 64 pad
                            // (944 dwords == 16 mod 32 banks -> upper-half lanes
                            //  de-aliased from lower half; 3712 was == 0 mod 128B
                            //  => 8-way conflict on every af read, r10: 3.73M)
#define WIN16 928           // 16B units per window (4 rows * 58 px * 4 sub)
#define EPQ (32*69*4)       // epilogue per-wave quadrant: [32 oc][69 px] f32 = 8832B
#define LDSB (4*EPQ)        // 35328 (A window 4*APL=15104 fits inside)

// workspace (bytes): two planar i8 tensors + transposed weights + flag
#define XBP_BYTES ((size_t)32*4*3364*64)          // 27,557,888
#define OFF_XBP2  (XBP_BYTES)
#define OFF_WBT   (2*XBP_BYTES)
#define WBT_BYTES ((size_t)9*16*256*16)           // 589,824
#define OFF_FLAG  (OFF_WBT + WBT_BYTES)
#define WS_NEED   (OFF_FLAG + 64)

// Fused prologue: block 0 = flag; blocks 1..256 = halo-zero; 257.. = w repack.
__global__ __launch_bounds__(256) void k_prep(
    const float* __restrict__ s1, const float* __restrict__ s2,
    const float* __restrict__ w, char* __restrict__ ws,
    char* __restrict__ wbTt, int* __restrict__ flag) {
    int b = blockIdx.x;
    int t = threadIdx.x;
    if (b == 0) {
        __shared__ int bad;
        if (t == 0) bad = 0;
        __syncthreads();
        if (s1[t] != s2[t]) atomicAdd(&bad, 1);
        __syncthreads();
        if (t == 0) *flag = (bad == 0) ? 1 : 0;
        return;
    }
    if (b <= 256) {
        char* base = ws + (size_t)(b - 1) * SLAB;
        int4 z = {0, 0, 0, 0};
#pragma unroll
        for (int i = 0; i < 4; ++i) {
            int u = t + i * 256;
            if (u >= 912) break;
            int off;
            if (u < 232)      off = u;
            else if (u < 464) off = 57 * 232 + (u - 232);
            else if (u < 688) { int r = (u - 464) >> 2; off = (r + 1) * 232 + ((u - 464) & 3); }
            else              { int r = (u - 688) >> 2; off = (r + 1) * 232 + 228 + ((u - 688) & 3); }
            *(int4*)(base + off * 16) = z;
        }
        return;
    }
    int idx = (b - 257) * 256 + t;               // 0..589823
    int kk = idx >> 16;
    int sub = (idx >> 12) & 15;
    int oc = (idx >> 4) & 255;
    int lo = idx & 15;
    float v = w[(oc * 256 + sub * 16 + lo) * 9 + kk];
    wbTt[idx] = (v > 0.f) ? (char)1 : ((v < 0.f) ? (char)-1 : (char)0);
}

// NCHW fp32 -> planar halo-padded i8: xbp[n][plane4][py][px][64] = sign(x+shift)
__global__ __launch_bounds__(256) void k_repack_x(
    const float* __restrict__ x, const float* __restrict__ sh1,
    const float* __restrict__ sh2, char* __restrict__ xbp1,
    char* __restrict__ xbp2, const int* __restrict__ flag) {
    __shared__ float lds[64 * 68];
    bool eq = (*flag != 0);
    int t = threadIdx.x;
    int b = blockIdx.x;
    int n = b / 49;
    int p0 = (b % 49) * 64;

    int pixw = t >> 2;
    int sub  = t & 3;
    int pw = p0 + pixw;
    int yw = pw / WW, xw = pw % WW;

    int cl = t >> 4;
    int p4 = (t & 15) * 4;

    for (int cc = 0; cc < 256; cc += 64) {
        __syncthreads();
#pragma unroll
        for (int i = 0; i < 4; ++i) {
            float4 v = *(const float4*)(x + (size_t)(n * 256 + cc + cl + i * 16) * PIX + p0 + p4);
            *(float4*)(&lds[(cl + i * 16) * 68 + p4]) = v;
        }
        __syncthreads();
        size_t obase = (size_t)(n * 4 + (cc >> 6)) * SLAB
                     + ((size_t)(yw + 1) * 58 + (xw + 1)) * 64 + sub * 16;
        union { char c[16]; int4 v; } u1, u2;
#pragma unroll
        for (int k = 0; k < 16; ++k) {
            int c = sub * 16 + k;
            float v = lds[c * 68 + pixw];
            float a1 = v + sh1[cc + c];
            float a2 = v + sh2[cc + c];
            u1.c[k] = (a1 > 0.f) ? (char)1 : ((a1 < 0.f) ? (char)-1 : (char)0);
            u2.c[k] = (a2 > 0.f) ? (char)1 : ((a2 < 0.f) ? (char)-1 : (char)0);
        }
        *(int4*)(xbp1 + obase) = u1.v;
        if (!eq) *(int4*)(xbp2 + obase) = u2.v;
    }
}

// Implicit-GEMM binary conv, i8 MFMA. Tile 64px x 256oc; 4 waves, wave = 64px x 64oc
// (acc 2x2x16 = 64 AGPR). Per phase: 2 bf L2->reg loads, 2 af ds_reads, 4 MFMA.
// bf ring: size 6, prefetch distance 5 (5 % 6 != 0 -> no slot collision).
// af: REGISTER DOUBLE-BUFFER - phase sl prefetches sl+1's fragments before its
// MFMA burst, so ds_read latency hides under the previous phase (r10 had the
// lgkmcnt(0) wait on the critical path of every phase).
// Nontemporal out stores keep the 103MB stream out of L2.
// MODE 0: EQ: out=(acc+b)*(1+w1). MODE 1: out=acc+(1+w1)b. MODE 2: out+=w1*acc.
template <int MODE>
__global__ __launch_bounds__(256, 3) void k_bgemm(
    const char* __restrict__ xsrc, const char* __restrict__ wbTt,
    const float* __restrict__ bias, const float* __restrict__ w1,
    const int* __restrict__ flag, float* __restrict__ out) {
    bool eq = (*flag != 0);
    if (MODE == 0 ? !eq : eq) return;    // block-uniform

    __shared__ char lds[LDSB];

    int t = threadIdx.x;
    int l = t & 63, wid = t >> 6;
    int r32 = l & 31, half = l >> 5;

    // XCD-chunked swizzle: 1568 = 8*196; consecutive logicals share window rows
    int logical = (blockIdx.x & 7) * 196 + (blockIdx.x >> 3);
    int n = logical / 49, tp = logical % 49;
    int p0 = tp * 64;
    int y0 = p0 / WW;                    // window = padded rows y0..y0+3
    int ocw = wid * 64;                  // this wave's 64-oc slice

    int wpm[2];
#pragma unroll
    for (int mi = 0; mi < 2; ++mi) {
        int g = p0 + mi * 32 + r32;      // < 3136 always
        int yg = g / WW, xg = g - yg * WW;
        wpm[mi] = (yg + 1 - y0) * 58 + xg + 1;
    }

    int4 rA[4];
    i32x4v bf[6][2];                     // [ring][nj]
    i32x4v afb[2][2];                    // [parity][mi] - af double-buffer

    auto loadRA = [&](int cc_) {
        const char* sb = xsrc + (size_t)(n * 4 + cc_) * SLAB + (size_t)y0 * GROW;
#pragma unroll
        for (int j = 0; j < 4; ++j) {
            int u = t + j * 256;
            if (u < WIN16) rA[j] = *(const int4*)(sb + u * 16);
        }
    };
    auto writeA = [&]() {
#pragma unroll
        for (int j = 0; j < 4; ++j) {
            int u = t + j * 256;
            if (u < WIN16) *(int4*)(lds + (u & 3) * APL + (u >> 2) * 16) = rA[j];
        }
    };
    auto loadB = [&](int rot, int sk) {  // sk = cc*18 + kk*2 + kq (compile-time)
        int cc_ = sk / 18, kk_ = (sk / 2) % 9, kq_ = sk & 1;
#pragma unroll
        for (int nj = 0; nj < 2; ++nj)
            bf[rot][nj] = *(const i32x4v*)(wbTt +
                (((size_t)((kk_ * 16 + cc_ * 4 + kq_ * 2 + half) * 256
                           + ocw + nj * 32 + r32)) << 4));
    };

    i32x16v acc[2][2];                   // [mi][nj]
#pragma unroll
    for (int mi = 0; mi < 2; ++mi)
#pragma unroll
        for (int nj = 0; nj < 2; ++nj)
#pragma unroll
            for (int i = 0; i < 16; ++i) acc[mi][nj][i] = 0;

    // invariant: B for phase sk lives in ring slot sk % 6
    loadRA(0);
    loadB(0, 0); loadB(1, 1); loadB(2, 2); loadB(3, 3); loadB(4, 4);

#pragma unroll
    for (int cc = 0; cc < 4; ++cc) {
        __syncthreads();                 // all waves done reading old window
        writeA();
        __syncthreads();                 // window ready
        // preload af for phase 0 (kk=0,kq=0): ts=-59, ci=half
        afb[0][0] = *(const i32x4v*)(lds + half * APL + (wpm[0] - 59) * 16);
        afb[0][1] = *(const i32x4v*)(lds + half * APL + (wpm[1] - 59) * 16);
#pragma unroll
        for (int kk = 0; kk < 9; ++kk) {
#pragma unroll
            for (int kq = 0; kq < 2; ++kq) {
                const int sl = kk * 2 + kq;          // 0..17 (compile-time)
                const int sk = cc * 18 + sl;
                const int par = sl & 1;
                if (sl < 17) {                       // prefetch next phase's af
                    const int nkk = (sl + 1) >> 1, nkq = (sl + 1) & 1;
                    const int nts = (nkk / 3 - 1) * 58 + (nkk % 3) - 1;
                    afb[par ^ 1][0] = *(const i32x4v*)(lds + (nkq * 2 + half) * APL
                                                       + (wpm[0] + nts) * 16);
                    afb[par ^ 1][1] = *(const i32x4v*)(lds + (nkq * 2 + half) * APL
                                                       + (wpm[1] + nts) * 16);
                }
                if (sk + 5 < 72) loadB((sk + 5) % 6, sk + 5);
                // A for next cc issued late so in-order vmcnt keeps B waits clean
                if (kk == 7 && kq == 1 && cc < 3) loadRA(cc + 1);
                const int cur = sk % 6;
                acc[0][0] = __builtin_amdgcn_mfma_i32_32x32x32_i8(afb[par][0], bf[cur][0], acc[0][0], 0, 0, 0);
                acc[0][1] = __builtin_amdgcn_mfma_i32_32x32x32_i8(afb[par][0], bf[cur][1], acc[0][1], 0, 0, 0);
                acc[1][0] = __builtin_amdgcn_mfma_i32_32x32x32_i8(afb[par][1], bf[cur][0], acc[1][0], 0, 0, 0);
                acc[1][1] = __builtin_amdgcn_mfma_i32_32x32x32_i8(afb[par][1], bf[cur][1], acc[1][1], 0, 0, 0);
            }
        }
    }

    // ---- epilogue: wave-private LDS transpose quadrant -> 256B nt stores ----
    __syncthreads();   // REQUIRED: quadrants overlay the A-window other waves read
    float w1v = w1[0];
    float se = 1.f + w1v;
    float* sb = (float*)(lds + wid * EPQ);   // [32 oc][69 px]
    size_t outb = (size_t)n * 256 * PIX + p0;

#pragma unroll
    for (int nj = 0; nj < 2; ++nj) {
        float bv = bias[ocw + nj * 32 + r32];
#pragma unroll
        for (int mi = 0; mi < 2; ++mi)
#pragma unroll
            for (int q = 0; q < 4; ++q) {
                f32x4 v;
#pragma unroll
                for (int j = 0; j < 4; ++j) {
                    float a = (float)(acc[mi][nj][q * 4 + j]);
                    if (MODE == 0)      v[j] = (a + bv) * se;
                    else if (MODE == 1) v[j] = a + se * bv;
                    else                v[j] = w1v * a;
                }
                *(f32x4*)(sb + r32 * 69 + mi * 32 + q * 8 + half * 4) = v;
            }
        asm volatile("s_waitcnt lgkmcnt(0)" ::: "memory");
#pragma unroll
        for (int p = 0; p < 8; ++p) {
            int row = p * 4 + (l >> 4);          // oc-rel 0..31
            int px4 = (l & 15) * 4;              // 0..60
            f32x4 v = *(const f32x4*)(sb + row * 69 + px4);
            float* op = out + outb + (size_t)(ocw + nj * 32 + row) * PIX + px4;
            if (MODE == 2) {
                f32x4 o = *(const f32x4*)op;
                v[0] += o[0]; v[1] += o[1]; v[2] += o[2]; v[3] += o[3];
            }
            __builtin_nontemporal_store(v, (f32x4*)op);
        }
        if (nj == 0) asm volatile("s_waitcnt lgkmcnt(0)" ::: "memory");
    }
}

extern "C" void kernel_launch(void* const* d_in, const int* in_sizes, int n_in,
                              void* d_out, int out_size, void* d_ws, size_t ws_size,
                              hipStream_t stream) {
    const float* x    = (const float*)d_in[0];
    const float* sh1  = (const float*)d_in[1];
    const float* sh2  = (const float*)d_in[2];
    const float* wgt  = (const float*)d_in[3];
    const float* bias = (const float*)d_in[4];
    const float* w1   = (const float*)d_in[5];
    float* out = (float*)d_out;
    char* ws = (char*)d_ws;
    if (ws_size < WS_NEED) return;

    char* xbp1 = ws;
    char* xbp2 = ws + OFF_XBP2;
    char* wbTt = ws + OFF_WBT;
    int* flag  = (int*)(ws + OFF_FLAG);

    k_prep<<<2561, 256, 0, stream>>>(sh1, sh2, wgt, ws, wbTt, flag);
    k_repack_x<<<32 * 49, 256, 0, stream>>>(x, sh1, sh2, xbp1, xbp2, flag);
    k_bgemm<0><<<1568, 256, 0, stream>>>(xbp1, wbTt, bias, w1, flag, out);
    k_bgemm<1><<<1568, 256, 0, stream>>>(xbp1, wbTt, bias, w1, flag, out);
    k_bgemm<2><<<1568, 256, 0, stream>>>(xbp2, wbTt, bias, w1, flag, out);
}

// Round 12
// 116.766 us; speedup vs baseline: 1.3444x; 1.0145x over previous
//
#include <hip/hip_runtime.h>
#include <stdint.h>

typedef __attribute__((ext_vector_type(4))) int   i32x4v;
typedef __attribute__((ext_vector_type(16))) int  i32x16v;
typedef __attribute__((ext_vector_type(4))) float f32x4;

#define PIX 3136            // 56*56
#define WW 56
#define SLAB 215296         // 58*58*64 bytes, one (n,chunk64) plane (global)
#define GROW 3712           // global bytes per padded row window-slice (58*64)
#define APL 3776            // LDS bytes per 16B-sub plane (232*16 + 64 pad,
                            //  de-aliases upper-half lanes; r11 finding)
#define ABUF 15104          // one A-window buffer: 4 * APL
#define WIN16 928           // 16B units per window (4 rows * 58 px * 4 sub)
#define EPQ (32*69*4)       // epilogue per-wave quadrant: [32 oc][69 px] f32 = 8832B
#define LDSB (4*EPQ)        // 35328; A dbuf 2*15104=30208 overlays it

// workspace (bytes): two planar i8 tensors + transposed weights + flag
#define XBP_BYTES ((size_t)32*4*3364*64)          // 27,557,888
#define OFF_XBP2  (XBP_BYTES)
#define OFF_WBT   (2*XBP_BYTES)
#define WBT_BYTES ((size_t)9*16*256*16)           // 589,824
#define OFF_FLAG  (OFF_WBT + WBT_BYTES)
#define WS_NEED   (OFF_FLAG + 64)

// Fused prologue: block 0 = flag; blocks 1..256 = halo-zero; 257.. = w repack.
__global__ __launch_bounds__(256) void k_prep(
    const float* __restrict__ s1, const float* __restrict__ s2,
    const float* __restrict__ w, char* __restrict__ ws,
    char* __restrict__ wbTt, int* __restrict__ flag) {
    int b = blockIdx.x;
    int t = threadIdx.x;
    if (b == 0) {
        __shared__ int bad;
        if (t == 0) bad = 0;
        __syncthreads();
        if (s1[t] != s2[t]) atomicAdd(&bad, 1);
        __syncthreads();
        if (t == 0) *flag = (bad == 0) ? 1 : 0;
        return;
    }
    if (b <= 256) {
        char* base = ws + (size_t)(b - 1) * SLAB;
        int4 z = {0, 0, 0, 0};
#pragma unroll
        for (int i = 0; i < 4; ++i) {
            int u = t + i * 256;
            if (u >= 912) break;
            int off;
            if (u < 232)      off = u;
            else if (u < 464) off = 57 * 232 + (u - 232);
            else if (u < 688) { int r = (u - 464) >> 2; off = (r + 1) * 232 + ((u - 464) & 3); }
            else              { int r = (u - 688) >> 2; off = (r + 1) * 232 + 228 + ((u - 688) & 3); }
            *(int4*)(base + off * 16) = z;
        }
        return;
    }
    int idx = (b - 257) * 256 + t;               // 0..589823
    int kk = idx >> 16;
    int sub = (idx >> 12) & 15;
    int oc = (idx >> 4) & 255;
    int lo = idx & 15;
    float v = w[(oc * 256 + sub * 16 + lo) * 9 + kk];
    wbTt[idx] = (v > 0.f) ? (char)1 : ((v < 0.f) ? (char)-1 : (char)0);
}

// NCHW fp32 -> planar halo-padded i8: xbp[n][plane4][py][px][64] = sign(x+shift)
__global__ __launch_bounds__(256) void k_repack_x(
    const float* __restrict__ x, const float* __restrict__ sh1,
    const float* __restrict__ sh2, char* __restrict__ xbp1,
    char* __restrict__ xbp2, const int* __restrict__ flag) {
    __shared__ float lds[64 * 68];
    bool eq = (*flag != 0);
    int t = threadIdx.x;
    int b = blockIdx.x;
    int n = b / 49;
    int p0 = (b % 49) * 64;

    int pixw = t >> 2;
    int sub  = t & 3;
    int pw = p0 + pixw;
    int yw = pw / WW, xw = pw % WW;

    int cl = t >> 4;
    int p4 = (t & 15) * 4;

    for (int cc = 0; cc < 256; cc += 64) {
        __syncthreads();
#pragma unroll
        for (int i = 0; i < 4; ++i) {
            float4 v = *(const float4*)(x + (size_t)(n * 256 + cc + cl + i * 16) * PIX + p0 + p4);
            *(float4*)(&lds[(cl + i * 16) * 68 + p4]) = v;
        }
        __syncthreads();
        size_t obase = (size_t)(n * 4 + (cc >> 6)) * SLAB
                     + ((size_t)(yw + 1) * 58 + (xw + 1)) * 64 + sub * 16;
        union { char c[16]; int4 v; } u1, u2;
#pragma unroll
        for (int k = 0; k < 16; ++k) {
            int c = sub * 16 + k;
            float v = lds[c * 68 + pixw];
            float a1 = v + sh1[cc + c];
            float a2 = v + sh2[cc + c];
            u1.c[k] = (a1 > 0.f) ? (char)1 : ((a1 < 0.f) ? (char)-1 : (char)0);
            u2.c[k] = (a2 > 0.f) ? (char)1 : ((a2 < 0.f) ? (char)-1 : (char)0);
        }
        *(int4*)(xbp1 + obase) = u1.v;
        if (!eq) *(int4*)(xbp2 + obase) = u2.v;
    }
}

// Implicit-GEMM binary conv, i8 MFMA. Tile 64px x 256oc; 4 waves, wave = 64px x 64oc.
// A-window DOUBLE-BUFFERED with T14 async-split staging: loadRA(cc+1) at phase 2,
// writeA(buf^1) at phase 15, ONE __syncthreads per cc (r11 had 2 -> every cc drained
// vmcnt(0)+lgkmcnt(0) and killed the bf ring's in-flight loads).
// bf ring size 6 / prefetch distance 5; af parity double-buffer; APL 3776 pad.
// MODE 0: EQ: out=(acc+b)*(1+w1). MODE 1: out=acc+(1+w1)b. MODE 2: out+=w1*acc.
template <int MODE>
__global__ __launch_bounds__(256, 3) void k_bgemm(
    const char* __restrict__ xsrc, const char* __restrict__ wbTt,
    const float* __restrict__ bias, const float* __restrict__ w1,
    const int* __restrict__ flag, float* __restrict__ out) {
    bool eq = (*flag != 0);
    if (MODE == 0 ? !eq : eq) return;    // block-uniform

    __shared__ char lds[LDSB];

    int t = threadIdx.x;
    int l = t & 63, wid = t >> 6;
    int r32 = l & 31, half = l >> 5;

    // XCD-chunked swizzle: 1568 = 8*196; consecutive logicals share window rows
    int logical = (blockIdx.x & 7) * 196 + (blockIdx.x >> 3);
    int n = logical / 49, tp = logical % 49;
    int p0 = tp * 64;
    int y0 = p0 / WW;                    // window = padded rows y0..y0+3
    int ocw = wid * 64;                  // this wave's 64-oc slice

    int wpm[2];
#pragma unroll
    for (int mi = 0; mi < 2; ++mi) {
        int g = p0 + mi * 32 + r32;      // < 3136 always
        int yg = g / WW, xg = g - yg * WW;
        wpm[mi] = (yg + 1 - y0) * 58 + xg + 1;
    }

    int4 rA[4];
    i32x4v bf[6][2];                     // [ring][nj]
    i32x4v afb[2][2];                    // [parity][mi]

    auto loadRA = [&](int cc_) {
        const char* sb = xsrc + (size_t)(n * 4 + cc_) * SLAB + (size_t)y0 * GROW;
#pragma unroll
        for (int j = 0; j < 4; ++j) {
            int u = t + j * 256;
            if (u < WIN16) rA[j] = *(const int4*)(sb + u * 16);
        }
    };
    auto writeA = [&](char* buf) {
#pragma unroll
        for (int j = 0; j < 4; ++j) {
            int u = t + j * 256;
            if (u < WIN16) *(int4*)(buf + (u & 3) * APL + (u >> 2) * 16) = rA[j];
        }
    };
    auto loadB = [&](int rot, int sk) {  // sk = cc*18 + kk*2 + kq (compile-time)
        int cc_ = sk / 18, kk_ = (sk / 2) % 9, kq_ = sk & 1;
#pragma unroll
        for (int nj = 0; nj < 2; ++nj)
            bf[rot][nj] = *(const i32x4v*)(wbTt +
                (((size_t)((kk_ * 16 + cc_ * 4 + kq_ * 2 + half) * 256
                           + ocw + nj * 32 + r32)) << 4));
    };

    i32x16v acc[2][2];                   // [mi][nj]
#pragma unroll
    for (int mi = 0; mi < 2; ++mi)
#pragma unroll
        for (int nj = 0; nj < 2; ++nj)
#pragma unroll
            for (int i = 0; i < 16; ++i) acc[mi][nj][i] = 0;

    // prologue: stage window 0 into buf0; preload bf ring (phase sk slot = sk%6)
    loadRA(0);
    loadB(0, 0); loadB(1, 1); loadB(2, 2); loadB(3, 3); loadB(4, 4);
    writeA(lds);                         // compiler waits vmcnt for rA only
    __syncthreads();

#pragma unroll
    for (int cc = 0; cc < 4; ++cc) {
        char* bp = lds + (cc & 1) * ABUF;        // read buffer (compile-time)
        char* bn = lds + ((cc & 1) ^ 1) * ABUF;  // write buffer for cc+1
        // preload af for phase 0 (kk=0,kq=0): ts=-59, ci=half
        afb[0][0] = *(const i32x4v*)(bp + half * APL + (wpm[0] - 59) * 16);
        afb[0][1] = *(const i32x4v*)(bp + half * APL + (wpm[1] - 59) * 16);
#pragma unroll
        for (int kk = 0; kk < 9; ++kk) {
#pragma unroll
            for (int kq = 0; kq < 2; ++kq) {
                const int sl = kk * 2 + kq;          // 0..17 (compile-time)
                const int sk = cc * 18 + sl;
                const int par = sl & 1;
                if (sl < 17) {                       // prefetch next phase's af
                    const int nkk = (sl + 1) >> 1, nkq = (sl + 1) & 1;
                    const int nts = (nkk / 3 - 1) * 58 + (nkk % 3) - 1;
                    afb[par ^ 1][0] = *(const i32x4v*)(bp + (nkq * 2 + half) * APL
                                                       + (wpm[0] + nts) * 16);
                    afb[par ^ 1][1] = *(const i32x4v*)(bp + (nkq * 2 + half) * APL
                                                       + (wpm[1] + nts) * 16);
                }
                if (sk + 5 < 72) loadB((sk + 5) % 6, sk + 5);
                if (sl == 2 && cc < 3) loadRA(cc + 1);      // issue early
                if (sl == 15 && cc < 3) writeA(bn);         // write late (T14)
                const int cur = sk % 6;
                acc[0][0] = __builtin_amdgcn_mfma_i32_32x32x32_i8(afb[par][0], bf[cur][0], acc[0][0], 0, 0, 0);
                acc[0][1] = __builtin_amdgcn_mfma_i32_32x32x32_i8(afb[par][0], bf[cur][1], acc[0][1], 0, 0, 0);
                acc[1][0] = __builtin_amdgcn_mfma_i32_32x32x32_i8(afb[par][1], bf[cur][0], acc[1][0], 0, 0, 0);
                acc[1][1] = __builtin_amdgcn_mfma_i32_32x32x32_i8(afb[par][1], bf[cur][1], acc[1][1], 0, 0, 0);
            }
        }
        __syncthreads();                 // ONE barrier per cc: buf ready + readers done
    }

    // ---- epilogue: wave-private LDS transpose quadrant -> 256B nt stores ----
    // (last barrier above already separates main-loop reads from quadrant writes)
    float w1v = w1[0];
    float se = 1.f + w1v;
    float* sb = (float*)(lds + wid * EPQ);   // [32 oc][69 px]
    size_t outb = (size_t)n * 256 * PIX + p0;

#pragma unroll
    for (int nj = 0; nj < 2; ++nj) {
        float bv = bias[ocw + nj * 32 + r32];
#pragma unroll
        for (int mi = 0; mi < 2; ++mi)
#pragma unroll
            for (int q = 0; q < 4; ++q) {
                f32x4 v;
#pragma unroll
                for (int j = 0; j < 4; ++j) {
                    float a = (float)(acc[mi][nj][q * 4 + j]);
                    if (MODE == 0)      v[j] = (a + bv) * se;
                    else if (MODE == 1) v[j] = a + se * bv;
                    else                v[j] = w1v * a;
                }
                *(f32x4*)(sb + r32 * 69 + mi * 32 + q * 8 + half * 4) = v;
            }
        asm volatile("s_waitcnt lgkmcnt(0)" ::: "memory");
#pragma unroll
        for (int p = 0; p < 8; ++p) {
            int row = p * 4 + (l >> 4);          // oc-rel 0..31
            int px4 = (l & 15) * 4;              // 0..60
            f32x4 v = *(const f32x4*)(sb + row * 69 + px4);
            float* op = out + outb + (size_t)(ocw + nj * 32 + row) * PIX + px4;
            if (MODE == 2) {
                f32x4 o = *(const f32x4*)op;
                v[0] += o[0]; v[1] += o[1]; v[2] += o[2]; v[3] += o[3];
            }
            __builtin_nontemporal_store(v, (f32x4*)op);
        }
        if (nj == 0) asm volatile("s_waitcnt lgkmcnt(0)" ::: "memory");
    }
}

extern "C" void kernel_launch(void* const* d_in, const int* in_sizes, int n_in,
                              void* d_out, int out_size, void* d_ws, size_t ws_size,
                              hipStream_t stream) {
    const float* x    = (const float*)d_in[0];
    const float* sh1  = (const float*)d_in[1];
    const float* sh2  = (const float*)d_in[2];
    const float* wgt  = (const float*)d_in[3];
    const float* bias = (const float*)d_in[4];
    const float* w1   = (const float*)d_in[5];
    float* out = (float*)d_out;
    char* ws = (char*)d_ws;
    if (ws_size < WS_NEED) return;

    char* xbp1 = ws;
    char* xbp2 = ws + OFF_XBP2;
    char* wbTt = ws + OFF_WBT;
    int* flag  = (int*)(ws + OFF_FLAG);

    k_prep<<<2561, 256, 0, stream>>>(sh1, sh2, wgt, ws, wbTt, flag);
    k_repack_x<<<32 * 49, 256, 0, stream>>>(x, sh1, sh2, xbp1, xbp2, flag);
    k_bgemm<0><<<1568, 256, 0, stream>>>(xbp1, wbTt, bias, w1, flag, out);
    k_bgemm<1><<<1568, 256, 0, stream>>>(xbp1, wbTt, bias, w1, flag, out);
    k_bgemm<2><<<1568, 256, 0, stream>>>(xbp2, wbTt, bias, w1, flag, out);
}

// Round 15
// 116.603 us; speedup vs baseline: 1.3463x; 1.0014x over previous
//
#include <hip/hip_runtime.h>
#include <stdint.h>

typedef __attribute__((ext_vector_type(4))) int   i32x4v;
typedef __attribute__((ext_vector_type(16))) int  i32x16v;
typedef __attribute__((ext_vector_type(4))) float f32x4;

#define PIX 3136            // 56*56
#define WW 56
#define SPL 53824           // sub-plane: 58*58*16 B
#define SLAB 215296         // one (n,cc64) slab = 4 sub-planes
#define ABUF 16384          // one A-window buffer (4 planes x 4096)
#define EPQ (32*69*4)       // epilogue per-wave quadrant: 8832 B
#define LDSB 65536          // A dbuf 32KB @0 + B dbuf 32KB @32768; epilogue overlays

// workspace (bytes): two sub-planar i8 tensors + transposed weights + flag
#define XBP_BYTES ((size_t)32*4*215296)           // 27,557,888
#define OFF_XBP2  (XBP_BYTES)
#define OFF_WBT   (2*XBP_BYTES)
#define WBT_BYTES ((size_t)9*16*256*16)           // 589,824
#define OFF_FLAG  (OFF_WBT + WBT_BYTES)
#define WS_NEED   (OFF_FLAG + 64)

// Fused prologue: block 0 = flag; blocks 1..256 = halo-zero; 257.. = w repack.
__global__ __launch_bounds__(256) void k_prep(
    const float* __restrict__ s1, const float* __restrict__ s2,
    const float* __restrict__ w, char* __restrict__ ws,
    char* __restrict__ wbTt, int* __restrict__ flag) {
    int b = blockIdx.x;
    int t = threadIdx.x;
    if (b == 0) {
        __shared__ int bad;
        if (t == 0) bad = 0;
        __syncthreads();
        if (s1[t] != s2[t]) atomicAdd(&bad, 1);
        __syncthreads();
        if (t == 0) *flag = (bad == 0) ? 1 : 0;
        return;
    }
    if (b <= 256) {
        // halo ring of one slab, sub-planar: 4 sub-planes x 228 16B-units
        char* base = ws + (size_t)(b - 1) * SLAB;
        int4 z = {0, 0, 0, 0};
#pragma unroll
        for (int i = 0; i < 4; ++i) {
            int u = t + i * 256;
            if (u >= 912) break;
            int s = u / 228, v = u - s * 228;
            int off;
            if (v < 58)       off = v;                       // top row
            else if (v < 116) off = 3306 + (v - 58);         // bottom row (57*58)
            else { int r = v - 116; off = ((r >> 1) + 1) * 58 + (r & 1) * 57; }
            *(int4*)(base + s * SPL + off * 16) = z;
        }
        return;
    }
    int idx = (b - 257) * 256 + t;               // 0..589823
    int kk = idx >> 16;
    int sub = (idx >> 12) & 15;
    int oc = (idx >> 4) & 255;
    int lo = idx & 15;
    float v = w[(oc * 256 + sub * 16 + lo) * 9 + kk];
    wbTt[idx] = (v > 0.f) ? (char)1 : ((v < 0.f) ? (char)-1 : (char)0);
}

// NCHW fp32 -> sub-planar halo-padded i8: xbp[n][cc][sub][py][px][16B] = sign(x+shift)
__global__ __launch_bounds__(256) void k_repack_x(
    const float* __restrict__ x, const float* __restrict__ sh1,
    const float* __restrict__ sh2, char* __restrict__ xbp1,
    char* __restrict__ xbp2, const int* __restrict__ flag) {
    __shared__ float lds[64 * 68];
    bool eq = (*flag != 0);
    int t = threadIdx.x;
    int b = blockIdx.x;
    int n = b / 49;
    int p0 = (b % 49) * 64;

    int pixw = t >> 2;
    int sub  = t & 3;
    int pw = p0 + pixw;
    int yw = pw / WW, xw = pw % WW;

    int cl = t >> 4;
    int p4 = (t & 15) * 4;

    for (int cc = 0; cc < 256; cc += 64) {
        __syncthreads();
#pragma unroll
        for (int i = 0; i < 4; ++i) {
            float4 v = *(const float4*)(x + (size_t)(n * 256 + cc + cl + i * 16) * PIX + p0 + p4);
            *(float4*)(&lds[(cl + i * 16) * 68 + p4]) = v;
        }
        __syncthreads();
        size_t obase = (size_t)(n * 4 + (cc >> 6)) * SLAB + (size_t)sub * SPL
                     + ((size_t)(yw + 1) * 58 + (xw + 1)) * 16;
        union { char c[16]; int4 v; } u1, u2;
#pragma unroll
        for (int k = 0; k < 16; ++k) {
            int c = sub * 16 + k;
            float v = lds[c * 68 + pixw];
            float a1 = v + sh1[cc + c];
            float a2 = v + sh2[cc + c];
            u1.c[k] = (a1 > 0.f) ? (char)1 : ((a1 < 0.f) ? (char)-1 : (char)0);
            u2.c[k] = (a2 > 0.f) ? (char)1 : ((a2 < 0.f) ? (char)-1 : (char)0);
        }
        *(int4*)(xbp1 + obase) = u1.v;
        if (!eq) *(int4*)(xbp2 + obase) = u2.v;
    }
}

// Implicit-GEMM binary conv, i8 MFMA — T3 2-phase template on 36 tap-phases (BK=64).
// Tile 64px x 256oc, 4 waves, wave = 64px x 64oc (acc 64 AGPR).
// Per tap: STAGE(t+1 via global_load_lds, issue-early) -> ds_read(t) -> 8 MFMA ->
// __syncthreads() (wait-late publication).
// r13/r14 BUG CHAIN: for LDS-DMA, vmcnt retires on MEMORY-return; the LDS WRITE
// is tracked by EXPCNT (m97 asm dump: compiler emits vmcnt(0) expcnt(0) lgkmcnt(0)
// before s_barrier). Hand-rolled "vmcnt(0); s_barrier" let waves read stale LDS
// in the memory-return->LDS-write window (absmax 52-54 = stale +-1 B-fragments).
// __syncthreads() drains ALL counters -> verified-correct publication (m97 idiom).
// NOTE: A-stage over-reads <=384B past the final slab (benign; stays inside d_ws).
// MODE 0: EQ: out=(acc+b)*(1+w1). MODE 1: out=acc+(1+w1)b. MODE 2: out+=w1*acc.
template <int MODE>
__global__ __launch_bounds__(256, 2) void k_bgemm(
    const char* __restrict__ xsrc, const char* __restrict__ wbTt,
    const float* __restrict__ bias, const float* __restrict__ w1,
    const int* __restrict__ flag, float* __restrict__ out) {
    bool eq = (*flag != 0);
    if (MODE == 0 ? !eq : eq) return;    // block-uniform

    __shared__ char lds[LDSB];

    int t = threadIdx.x;
    int l = t & 63, wid = t >> 6;
    int r32 = l & 31, half = l >> 5;

    // XCD-chunked swizzle: 1568 = 8*196; consecutive logicals share window rows
    int logical = (blockIdx.x & 7) * 196 + (blockIdx.x >> 3);
    int n = logical / 49, tp = logical % 49;
    int p0 = tp * 64;
    int y0 = p0 / WW;                    // window rows y0..y0+3 (y0 <= 54)
    int ocw = wid * 64;

    int wpm[2];
#pragma unroll
    for (int mi = 0; mi < 2; ++mi) {
        int g = p0 + mi * 32 + r32;      // < 3136 always
        int yg = g / WW, xg = g - yg * WW;
        wpm[mi] = (yg + 1 - y0) * 58 + xg + 1;   // 16B-unit index within plane
    }

    // stage one 16KB B tile (cc,kk) -> Bbuf[par]; layout [sub4][oc256][16B]
    auto stageB = [&](int par, int t2) {         // t2 compile-time
        const int cc2 = t2 / 9, kk2 = t2 % 9;
        const char* src = wbTt + kk2 * 65536 + cc2 * 16384 + wid * 4096 + l * 16;
        char* dst = lds + 32768 + par * 16384 + wid * 4096;
#pragma unroll
        for (int j = 0; j < 4; ++j)
            __builtin_amdgcn_global_load_lds(
                (const __attribute__((address_space(1))) void*)(src + j * 1024),
                (__attribute__((address_space(3))) void*)(dst + j * 1024), 16, 0, 0);
    };
    // stage 16KB A window (4 sub-planes x 4096B, wave w stages sub w) -> Abuf[par]
    auto stageA = [&](int par, int cc2) {
        const char* src = xsrc + (size_t)(n * 4 + cc2) * SLAB + (size_t)wid * SPL
                        + y0 * 928 + l * 16;
        char* dst = lds + par * ABUF + wid * 4096;
#pragma unroll
        for (int j = 0; j < 4; ++j)
            __builtin_amdgcn_global_load_lds(
                (const __attribute__((address_space(1))) void*)(src + j * 1024),
                (__attribute__((address_space(3))) void*)(dst + j * 1024), 16, 0, 0);
    };

    i32x16v acc[2][2];                   // [mi][nj]
#pragma unroll
    for (int mi = 0; mi < 2; ++mi)
#pragma unroll
        for (int nj = 0; nj < 2; ++nj)
#pragma unroll
            for (int i = 0; i < 16; ++i) acc[mi][nj][i] = 0;

    // prologue: A(cc=0) + B(tap 0), publish via full-counter sync (m97 idiom)
    stageA(0, 0);
    stageB(0, 0);
    __syncthreads();

#pragma unroll
    for (int tix = 0; tix < 36; ++tix) {
        const int cc = tix / 9, kk = tix % 9;
        if (tix < 35) stageB((tix + 1) & 1, tix + 1);        // issue-early
        if (kk == 4 && cc < 3) stageA((cc + 1) & 1, cc + 1);
        const int ts = (kk / 3 - 1) * 58 + (kk % 3) - 1;
        const char* Ab = lds + (cc & 1) * ABUF;
        const char* Bb = lds + 32768 + (tix & 1) * 16384;
#pragma unroll
        for (int kq = 0; kq < 2; ++kq) {
            const int ci = kq * 2 + half;
            i32x4v af0 = *(const i32x4v*)(Ab + ci * 4096 + (wpm[0] + ts) * 16);
            i32x4v af1 = *(const i32x4v*)(Ab + ci * 4096 + (wpm[1] + ts) * 16);
            i32x4v bf0 = *(const i32x4v*)(Bb + ci * 4096 + (ocw + r32) * 16);
            i32x4v bf1 = *(const i32x4v*)(Bb + ci * 4096 + (ocw + 32 + r32) * 16);
            acc[0][0] = __builtin_amdgcn_mfma_i32_32x32x32_i8(af0, bf0, acc[0][0], 0, 0, 0);
            acc[0][1] = __builtin_amdgcn_mfma_i32_32x32x32_i8(af0, bf1, acc[0][1], 0, 0, 0);
            acc[1][0] = __builtin_amdgcn_mfma_i32_32x32x32_i8(af1, bf0, acc[1][0], 0, 0, 0);
            acc[1][1] = __builtin_amdgcn_mfma_i32_32x32x32_i8(af1, bf1, acc[1][1], 0, 0, 0);
        }
        // wait-late: drain vmcnt+EXPCNT+lgkm and publish t+1's tiles to all waves
        __syncthreads();
    }

    // ---- epilogue: wave-private LDS transpose quadrant -> 256B nt stores ----
    // (final __syncthreads above separates main-loop reads from quadrant writes)
    float w1v = w1[0];
    float se = 1.f + w1v;
    float* sb = (float*)(lds + wid * EPQ);   // [32 oc][69 px]
    size_t outb = (size_t)n * 256 * PIX + p0;

#pragma unroll
    for (int nj = 0; nj < 2; ++nj) {
        float bv = bias[ocw + nj * 32 + r32];
#pragma unroll
        for (int mi = 0; mi < 2; ++mi)
#pragma unroll
            for (int q = 0; q < 4; ++q) {
                f32x4 v;
#pragma unroll
                for (int j = 0; j < 4; ++j) {
                    float a = (float)(acc[mi][nj][q * 4 + j]);
                    if (MODE == 0)      v[j] = (a + bv) * se;
                    else if (MODE == 1) v[j] = a + se * bv;
                    else                v[j] = w1v * a;
                }
                *(f32x4*)(sb + r32 * 69 + mi * 32 + q * 8 + half * 4) = v;
            }
        asm volatile("s_waitcnt lgkmcnt(0)" ::: "memory");
#pragma unroll
        for (int p = 0; p < 8; ++p) {
            int row = p * 4 + (l >> 4);          // oc-rel 0..31
            int px4 = (l & 15) * 4;              // 0..60
            f32x4 v = *(const f32x4*)(sb + row * 69 + px4);
            float* op = out + outb + (size_t)(ocw + nj * 32 + row) * PIX + px4;
            if (MODE == 2) {
                f32x4 o = *(const f32x4*)op;
                v[0] += o[0]; v[1] += o[1]; v[2] += o[2]; v[3] += o[3];
            }
            __builtin_nontemporal_store(v, (f32x4*)op);
        }
        if (nj == 0) asm volatile("s_waitcnt lgkmcnt(0)" ::: "memory");
    }
}

extern "C" void kernel_launch(void* const* d_in, const int* in_sizes, int n_in,
                              void* d_out, int out_size, void* d_ws, size_t ws_size,
                              hipStream_t stream) {
    const float* x    = (const float*)d_in[0];
    const float* sh1  = (const float*)d_in[1];
    const float* sh2  = (const float*)d_in[2];
    const float* wgt  = (const float*)d_in[3];
    const float* bias = (const float*)d_in[4];
    const float* w1   = (const float*)d_in[5];
    float* out = (float*)d_out;
    char* ws = (char*)d_ws;
    if (ws_size < WS_NEED) return;

    char* xbp1 = ws;
    char* xbp2 = ws + OFF_XBP2;
    char* wbTt = ws + OFF_WBT;
    int* flag  = (int*)(ws + OFF_FLAG);

    k_prep<<<2561, 256, 0, stream>>>(sh1, sh2, wgt, ws, wbTt, flag);
    k_repack_x<<<32 * 49, 256, 0, stream>>>(x, sh1, sh2, xbp1, xbp2, flag);
    k_bgemm<0><<<1568, 256, 0, stream>>>(xbp1, wbTt, bias, w1, flag, out);
    k_bgemm<1><<<1568, 256, 0, stream>>>(xbp1, wbTt, bias, w1, flag, out);
    k_bgemm<2><<<1568, 256, 0, stream>>>(xbp2, wbTt, bias, w1, flag, out);
}

// Round 16
// 105.467 us; speedup vs baseline: 1.4884x; 1.1056x over previous
//
#include <hip/hip_runtime.h>
#include <stdint.h>

typedef __attribute__((ext_vector_type(4))) int   i32x4v;
typedef __attribute__((ext_vector_type(16))) int  i32x16v;
typedef __attribute__((ext_vector_type(4))) float f32x4;

#define PIX 3136            // 56*56
#define WW 56
#define SPL 53824           // sub-plane: 58*58*16 B
#define SLAB 215296         // one (n,cc64) slab = 4 sub-planes
#define APL 5184            // LDS bytes per A sub-plane (290 units=4640 + pad;
                            //  1296 dwords == 16 mod 32 banks -> half-lanes de-aliased)
#define ABASE 16384         // A window base (B dbuf below it)
#define EPQ (32*69*4)       // epilogue per-wave quadrant: 8832 B
#define LDSB 37120          // B dbuf 16384 @0 + A 20736 @16384; epilogue 35328 overlays

// workspace (bytes): two sub-planar i8 tensors + transposed weights + flag
#define XBP_BYTES ((size_t)32*4*215296)           // 27,557,888
#define OFF_XBP2  (XBP_BYTES)
#define OFF_WBT   (2*XBP_BYTES)
#define WBT_BYTES ((size_t)9*16*256*16)           // 589,824
#define OFF_FLAG  (OFF_WBT + WBT_BYTES)
#define WS_NEED   (OFF_FLAG + 64)

// Fused prologue: block 0 = flag; blocks 1..256 = halo-zero; 257.. = w repack.
__global__ __launch_bounds__(256) void k_prep(
    const float* __restrict__ s1, const float* __restrict__ s2,
    const float* __restrict__ w, char* __restrict__ ws,
    char* __restrict__ wbTt, int* __restrict__ flag) {
    int b = blockIdx.x;
    int t = threadIdx.x;
    if (b == 0) {
        __shared__ int bad;
        if (t == 0) bad = 0;
        __syncthreads();
        if (s1[t] != s2[t]) atomicAdd(&bad, 1);
        __syncthreads();
        if (t == 0) *flag = (bad == 0) ? 1 : 0;
        return;
    }
    if (b <= 256) {
        // halo ring of one slab, sub-planar: 4 sub-planes x 228 16B-units
        char* base = ws + (size_t)(b - 1) * SLAB;
        int4 z = {0, 0, 0, 0};
#pragma unroll
        for (int i = 0; i < 4; ++i) {
            int u = t + i * 256;
            if (u >= 912) break;
            int s = u / 228, v = u - s * 228;
            int off;
            if (v < 58)       off = v;                       // top row
            else if (v < 116) off = 3306 + (v - 58);         // bottom row (57*58)
            else { int r = v - 116; off = ((r >> 1) + 1) * 58 + (r & 1) * 57; }
            *(int4*)(base + s * SPL + off * 16) = z;
        }
        return;
    }
    int idx = (b - 257) * 256 + t;               // 0..589823
    int kk = idx >> 16;
    int sub = (idx >> 12) & 15;
    int oc = (idx >> 4) & 255;
    int lo = idx & 15;
    float v = w[(oc * 256 + sub * 16 + lo) * 9 + kk];
    wbTt[idx] = (v > 0.f) ? (char)1 : ((v < 0.f) ? (char)-1 : (char)0);
}

// NCHW fp32 -> sub-planar halo-padded i8: xbp[n][cc][sub][py][px][16B] = sign(x+shift)
__global__ __launch_bounds__(256) void k_repack_x(
    const float* __restrict__ x, const float* __restrict__ sh1,
    const float* __restrict__ sh2, char* __restrict__ xbp1,
    char* __restrict__ xbp2, const int* __restrict__ flag) {
    __shared__ float lds[64 * 68];
    bool eq = (*flag != 0);
    int t = threadIdx.x;
    int b = blockIdx.x;
    int n = b / 49;
    int p0 = (b % 49) * 64;

    int pixw = t >> 2;
    int sub  = t & 3;
    int pw = p0 + pixw;
    int yw = pw / WW, xw = pw % WW;

    int cl = t >> 4;
    int p4 = (t & 15) * 4;

    for (int cc = 0; cc < 256; cc += 64) {
        __syncthreads();
#pragma unroll
        for (int i = 0; i < 4; ++i) {
            float4 v = *(const float4*)(x + (size_t)(n * 256 + cc + cl + i * 16) * PIX + p0 + p4);
            *(float4*)(&lds[(cl + i * 16) * 68 + p4]) = v;
        }
        __syncthreads();
        size_t obase = (size_t)(n * 4 + (cc >> 6)) * SLAB + (size_t)sub * SPL
                     + ((size_t)(yw + 1) * 58 + (xw + 1)) * 16;
        union { char c[16]; int4 v; } u1, u2;
#pragma unroll
        for (int k = 0; k < 16; ++k) {
            int c = sub * 16 + k;
            float v = lds[c * 68 + pixw];
            float a1 = v + sh1[cc + c];
            float a2 = v + sh2[cc + c];
            u1.c[k] = (a1 > 0.f) ? (char)1 : ((a1 < 0.f) ? (char)-1 : (char)0);
            u2.c[k] = (a2 > 0.f) ? (char)1 : ((a2 < 0.f) ? (char)-1 : (char)0);
        }
        *(int4*)(xbp1 + obase) = u1.v;
        if (!eq) *(int4*)(xbp2 + obase) = u2.v;
    }
}

// Implicit-GEMM binary conv, i8 MFMA. Tile 128px x 128oc (r15 was 64px x 256oc):
// per-block B traffic HALVED (288KB vs 576KB; aggregate 903->451MB) - r15's binder
// was per-tap L2 B-restaging drained by __syncthreads. 4 waves (2px x 2oc), wave =
// 64px x 64oc (acc 64 AGPR). B dbuf 16KB (8KB/tap) + A single-buf 20.7KB (5 rows,
// gload_lds, restaged once per cc in a dedicated barrier slot after readers-done).
// All publication via __syncthreads (r15-proven; r13/r14 raw-barrier race).
// Tail tile tp=24 half-valid: wpm clamp + guarded stores.
// MODE 0: EQ: out=(acc+b)*(1+w1). MODE 1: out=acc+(1+w1)b. MODE 2: out+=w1*acc.
template <int MODE>
__global__ __launch_bounds__(256, 3) void k_bgemm(
    const char* __restrict__ xsrc, const char* __restrict__ wbTt,
    const float* __restrict__ bias, const float* __restrict__ w1,
    const int* __restrict__ flag, float* __restrict__ out) {
    bool eq = (*flag != 0);
    if (MODE == 0 ? !eq : eq) return;    // block-uniform

    __shared__ char lds[LDSB];

    int t = threadIdx.x;
    int l = t & 63, wid = t >> 6;
    int wr = wid >> 1, wc = wid & 1;
    int r32 = l & 31, half = l >> 5;

    // XCD-chunked swizzle: 1600 = 8*200; ntile fastest -> both oc-tiles of a
    // window on one XCD (A L2-shared); adjacent tp share window rows.
    int logical = (blockIdx.x & 7) * 200 + (blockIdx.x >> 3);
    int ntile = logical & 1;
    int m = logical >> 1;                // 0..799
    int n = m / 25, tp = m % 25;
    int p0 = tp * 128;                   // tp=24: half-valid tile (px 3072..3135)
    int y0 = p0 / WW;
    int y0c = (y0 < 53) ? y0 : 53;       // 5-row window rows y0c..y0c+4 (<=57)
    int ocb = ntile * 128 + wc * 64;     // wave's absolute oc base
    int pxb = p0 + wr * 64;              // wave's pixel base
    bool pvalid = pxb < PIX;

    int wpm[2];
#pragma unroll
    for (int mi = 0; mi < 2; ++mi) {
        int g = pxb + mi * 32 + r32;
        if (g > 3135) g = 3135;          // only in store-disabled waves
        int yg = g / WW, xg = g - yg * WW;
        wpm[mi] = (yg + 1 - y0c) * 58 + xg + 1;  // 16B-unit index in plane
    }

    // stage one 8KB B tile (cc,kk, this block's 128 oc) -> Bbuf[par]
    // layout [ci4][oc128][16B]; wave w stages ci=w (2 x 1KB DMAs)
    auto stageB = [&](int par, int t2) {         // t2 compile-time
        const int cc2 = t2 / 9, kk2 = t2 % 9;
        const char* src = wbTt
            + ((size_t)((kk2 * 16 + cc2 * 4 + wid) * 256 + ntile * 128)) * 16 + l * 16;
        char* dst = lds + par * 8192 + wid * 2048;
#pragma unroll
        for (int j = 0; j < 2; ++j)
            __builtin_amdgcn_global_load_lds(
                (const __attribute__((address_space(1))) void*)(src + j * 1024),
                (__attribute__((address_space(3))) void*)(dst + j * 1024), 16, 0, 0);
    };
    // stage A window (4 sub-planes x 5 rows; wave w stages plane w, 5 x 1KB DMAs;
    // over-stages 480B/plane past the window - benign, lands in pad, src in d_ws)
    auto stageA = [&](int cc2) {
        const char* src = xsrc + (size_t)(n * 4 + cc2) * SLAB + (size_t)wid * SPL
                        + y0c * 928 + l * 16;
        char* dst = lds + ABASE + wid * APL;
#pragma unroll
        for (int j = 0; j < 5; ++j)
            __builtin_amdgcn_global_load_lds(
                (const __attribute__((address_space(1))) void*)(src + j * 1024),
                (__attribute__((address_space(3))) void*)(dst + j * 1024), 16, 0, 0);
    };

    i32x16v acc[2][2];                   // [mi][nj]
#pragma unroll
    for (int mi = 0; mi < 2; ++mi)
#pragma unroll
        for (int nj = 0; nj < 2; ++nj)
#pragma unroll
            for (int i = 0; i < 16; ++i) acc[mi][nj][i] = 0;

    // prologue: A(cc=0) + B(tap 0), publish (full-counter drain - m97 idiom)
    stageA(0);
    stageB(0, 0);
    __syncthreads();

#pragma unroll
    for (int cc = 0; cc < 4; ++cc) {
#pragma unroll
        for (int kk = 0; kk < 9; ++kk) {
            const int tix = cc * 9 + kk;
            if (tix < 35) stageB((tix + 1) & 1, tix + 1);    // issue-early
            const int ts = (kk / 3 - 1) * 58 + (kk % 3) - 1;
            const char* Ab = lds + ABASE;
            const char* Bb = lds + (tix & 1) * 8192;
#pragma unroll
            for (int kq = 0; kq < 2; ++kq) {
                const int ci = kq * 2 + half;
                i32x4v af0 = *(const i32x4v*)(Ab + ci * APL + (wpm[0] + ts) * 16);
                i32x4v af1 = *(const i32x4v*)(Ab + ci * APL + (wpm[1] + ts) * 16);
                i32x4v bf0 = *(const i32x4v*)(Bb + ci * 2048 + (wc * 64 + r32) * 16);
                i32x4v bf1 = *(const i32x4v*)(Bb + ci * 2048 + (wc * 64 + 32 + r32) * 16);
                acc[0][0] = __builtin_amdgcn_mfma_i32_32x32x32_i8(af0, bf0, acc[0][0], 0, 0, 0);
                acc[0][1] = __builtin_amdgcn_mfma_i32_32x32x32_i8(af0, bf1, acc[0][1], 0, 0, 0);
                acc[1][0] = __builtin_amdgcn_mfma_i32_32x32x32_i8(af1, bf0, acc[1][0], 0, 0, 0);
                acc[1][1] = __builtin_amdgcn_mfma_i32_32x32x32_i8(af1, bf1, acc[1][1], 0, 0, 0);
            }
            __syncthreads();             // publish t+1's B; readers of tap t done
        }
        // cc boundary: A readers done (last sync above) -> restage A, publish
        if (cc < 3) {
            stageA(cc + 1);
            __syncthreads();
        }
    }

    // ---- epilogue: wave-private LDS transpose quadrant -> 256B nt stores ----
    // (final __syncthreads above separates main-loop reads from quadrant writes)
    float w1v = w1[0];
    float se = 1.f + w1v;
    float* sb = (float*)(lds + wid * EPQ);   // [32 oc][69 px]
    size_t outb = (size_t)n * 256 * PIX + pxb;

#pragma unroll
    for (int nj = 0; nj < 2; ++nj) {
        float bv = bias[ocb + nj * 32 + r32];
#pragma unroll
        for (int mi = 0; mi < 2; ++mi)
#pragma unroll
            for (int q = 0; q < 4; ++q) {
                f32x4 v;
#pragma unroll
                for (int j = 0; j < 4; ++j) {
                    float a = (float)(acc[mi][nj][q * 4 + j]);
                    if (MODE == 0)      v[j] = (a + bv) * se;
                    else if (MODE == 1) v[j] = a + se * bv;
                    else                v[j] = w1v * a;
                }
                *(f32x4*)(sb + r32 * 69 + mi * 32 + q * 8 + half * 4) = v;
            }
        asm volatile("s_waitcnt lgkmcnt(0)" ::: "memory");
        if (pvalid) {
#pragma unroll
            for (int p = 0; p < 8; ++p) {
                int row = p * 4 + (l >> 4);          // oc-rel 0..31
                int px4 = (l & 15) * 4;              // 0..60
                f32x4 v = *(const f32x4*)(sb + row * 69 + px4);
                float* op = out + outb + (size_t)(ocb + nj * 32 + row) * PIX + px4;
                if (MODE == 2) {
                    f32x4 o = *(const f32x4*)op;
                    v[0] += o[0]; v[1] += o[1]; v[2] += o[2]; v[3] += o[3];
                }
                __builtin_nontemporal_store(v, (f32x4*)op);
            }
        }
        if (nj == 0) asm volatile("s_waitcnt lgkmcnt(0)" ::: "memory");
    }
}

extern "C" void kernel_launch(void* const* d_in, const int* in_sizes, int n_in,
                              void* d_out, int out_size, void* d_ws, size_t ws_size,
                              hipStream_t stream) {
    const float* x    = (const float*)d_in[0];
    const float* sh1  = (const float*)d_in[1];
    const float* sh2  = (const float*)d_in[2];
    const float* wgt  = (const float*)d_in[3];
    const float* bias = (const float*)d_in[4];
    const float* w1   = (const float*)d_in[5];
    float* out = (float*)d_out;
    char* ws = (char*)d_ws;
    if (ws_size < WS_NEED) return;

    char* xbp1 = ws;
    char* xbp2 = ws + OFF_XBP2;
    char* wbTt = ws + OFF_WBT;
    int* flag  = (int*)(ws + OFF_FLAG);

    k_prep<<<2561, 256, 0, stream>>>(sh1, sh2, wgt, ws, wbTt, flag);
    k_repack_x<<<32 * 49, 256, 0, stream>>>(x, sh1, sh2, xbp1, xbp2, flag);
    k_bgemm<0><<<1600, 256, 0, stream>>>(xbp1, wbTt, bias, w1, flag, out);
    k_bgemm<1><<<1600, 256, 0, stream>>>(xbp1, wbTt, bias, w1, flag, out);
    k_bgemm<2><<<1600, 256, 0, stream>>>(xbp2, wbTt, bias, w1, flag, out);
}